// Round 1
// baseline (725.394 us; speedup 1.0000x reference)
//
#include <hip/hip_runtime.h>

#define NN 100000
#define NE 1600000
#define FIN 32
#define FHID 64

__global__ void k_init_deg(float* __restrict__ deg) {
    int i = blockIdx.x * blockDim.x + threadIdx.x;
    if (i < NN) deg[i] = 1.0f;   // self-loop weight
}

__global__ void k_edge_deg(const int* __restrict__ col, const float* __restrict__ ew,
                           float* __restrict__ deg) {
    int e = blockIdx.x * blockDim.x + threadIdx.x;
    if (e < NE) atomicAdd(&deg[col[e]], ew[e]);
}

__global__ void k_rsqrt(float* __restrict__ deg) {
    int i = blockIdx.x * blockDim.x + threadIdx.x;
    if (i < NN) {
        float d = deg[i];
        deg[i] = d > 0.0f ? rsqrtf(d) : 0.0f;
    }
}

__global__ void k_coeff(const int* __restrict__ row, const int* __restrict__ col,
                        const float* __restrict__ ew, const float* __restrict__ dinv,
                        float* __restrict__ coeff) {
    int e = blockIdx.x * blockDim.x + threadIdx.x;
    if (e < NE) coeff[e] = dinv[row[e]] * ew[e] * dinv[col[e]];
}

// Y[n, of] = sum_k X[n,k] * W[k,of]   (W row-major [IN, OUT], staged in LDS)
template<int IN, int OUT>
__global__ void k_gemm(const float* __restrict__ X, const float* __restrict__ W,
                       float* __restrict__ Y) {
    __shared__ float sW[IN * OUT];
    for (int i = threadIdx.x; i < IN * OUT; i += blockDim.x) sW[i] = W[i];
    __syncthreads();
    int idx = blockIdx.x * blockDim.x + threadIdx.x;
    if (idx >= NN * OUT) return;
    int n = idx / OUT;
    int of = idx - n * OUT;
    const float* xr = X + (size_t)n * IN;
    float acc = 0.0f;
#pragma unroll
    for (int k = 0; k < IN; ++k) acc = fmaf(xr[k], sW[k * OUT + of], acc);
    Y[idx] = acc;
}

// dst[col[e]*F + f] += coeff[e] * src[row[e]*F + f]
// idx layout: e = idx/F, f = idx%F  -> a wave covers contiguous features of
// one (or two) edges: coalesced gather, no intra-wave atomic conflicts.
template<int F>
__global__ void k_scatter(const int* __restrict__ row, const int* __restrict__ col,
                          const float* __restrict__ coeff, const float* __restrict__ src,
                          float* __restrict__ dst) {
    int idx = blockIdx.x * blockDim.x + threadIdx.x;
    if (idx >= NE * F) return;
    int e = idx / F;
    int f = idx - e * F;
    float v = coeff[e] * src[(size_t)row[e] * F + f];
    atomicAdd(&dst[(size_t)col[e] * F + f], v);
}

// h = relu(dinv^2 * xw + acc + b)  (in place into acc)
__global__ void k_finish1(const float* __restrict__ xw, const float* __restrict__ dinv,
                          const float* __restrict__ b, float* __restrict__ acc) {
    int idx = blockIdx.x * blockDim.x + threadIdx.x;
    if (idx >= NN * FHID) return;
    int n = idx / FHID;
    int k = idx - n * FHID;
    float di = dinv[n];
    float v = acc[idx] + di * di * xw[idx] + b[k];
    acc[idx] = v > 0.0f ? v : 0.0f;
}

// out = relu(out + dinv^2 * hw + b)  (in place into d_out)
__global__ void k_finish2(const float* __restrict__ hw, const float* __restrict__ dinv,
                          const float* __restrict__ b, float* __restrict__ out) {
    int idx = blockIdx.x * blockDim.x + threadIdx.x;
    if (idx >= NN * FIN) return;
    int n = idx / FIN;
    int f = idx - n * FIN;
    float di = dinv[n];
    float v = out[idx] + di * di * hw[idx] + b[f];
    out[idx] = v > 0.0f ? v : 0.0f;
}

extern "C" void kernel_launch(void* const* d_in, const int* in_sizes, int n_in,
                              void* d_out, int out_size, void* d_ws, size_t ws_size,
                              hipStream_t stream) {
    const float* x  = (const float*)d_in[0];
    const int*   ei = (const int*)d_in[1];
    const float* ea = (const float*)d_in[2];
    const float* W1 = (const float*)d_in[3];
    const float* b1 = (const float*)d_in[4];
    const float* W2 = (const float*)d_in[5];
    const float* b2 = (const float*)d_in[6];
    float* out = (float*)d_out;

    const int* row = ei;        // edge_index[0]
    const int* col = ei + NE;   // edge_index[1]

    float* ws    = (float*)d_ws;
    float* deg   = ws;                        // NN   (becomes dinv in place)
    float* coeff = deg + NN;                  // NE
    float* xw1   = coeff + NE;                // NN*FHID
    float* acc1  = xw1 + (size_t)NN * FHID;   // NN*FHID (becomes h in place)
    float* hw2   = acc1 + (size_t)NN * FHID;  // NN*FIN

    const int B = 256;
    auto cdiv = [](long long a, int b) { return (int)((a + b - 1) / b); };

    // zero accumulators (capture-safe async memset)
    hipMemsetAsync(acc1, 0, sizeof(float) * (size_t)NN * FHID, stream);
    hipMemsetAsync(out, 0, sizeof(float) * (size_t)NN * FIN, stream);

    k_init_deg<<<cdiv(NN, B), B, 0, stream>>>(deg);
    k_edge_deg<<<cdiv(NE, B), B, 0, stream>>>(col, ea, deg);
    k_rsqrt<<<cdiv(NN, B), B, 0, stream>>>(deg);
    k_coeff<<<cdiv(NE, B), B, 0, stream>>>(row, col, ea, deg, coeff);

    // layer 1
    k_gemm<FIN, FHID><<<cdiv((long long)NN * FHID, B), B, 0, stream>>>(x, W1, xw1);
    k_scatter<FHID><<<cdiv((long long)NE * FHID, B), B, 0, stream>>>(row, col, coeff, xw1, acc1);
    k_finish1<<<cdiv((long long)NN * FHID, B), B, 0, stream>>>(xw1, deg, b1, acc1);

    // layer 2
    k_gemm<FHID, FIN><<<cdiv((long long)NN * FIN, B), B, 0, stream>>>(acc1, W2, hw2);
    k_scatter<FIN><<<cdiv((long long)NE * FIN, B), B, 0, stream>>>(row, col, coeff, hw2, out);
    k_finish2<<<cdiv((long long)NN * FIN, B), B, 0, stream>>>(hw2, deg, b2, out);

    // second output: edge_attr passthrough
    hipMemcpyAsync(out + (size_t)NN * FIN, ea, sizeof(float) * (size_t)NE,
                   hipMemcpyDeviceToDevice, stream);
}

// Round 2
// 516.865 us; speedup vs baseline: 1.4035x; 1.4035x over previous
//
#include <hip/hip_runtime.h>

#define NN 100000
#define NE 1600000
#define FIN 32
#define FHID 64
#define SCAN_B 1024
#define SCAN_NB ((NN + SCAN_B - 1) / SCAN_B)   // 98

// ---------- degree / norm ----------
__global__ void k_init_deg(float* __restrict__ deg) {
    int i = blockIdx.x * blockDim.x + threadIdx.x;
    if (i < NN) deg[i] = 1.0f;   // self-loop weight
}

// deg[col] += ew ; count[col] += 1   (fused single pass over edges)
__global__ void k_hist(const int* __restrict__ col, const float* __restrict__ ew,
                       float* __restrict__ deg, int* __restrict__ count) {
    int e = blockIdx.x * blockDim.x + threadIdx.x;
    if (e < NE) {
        int c = col[e];
        atomicAdd(&deg[c], ew[e]);
        atomicAdd(&count[c], 1);
    }
}

__global__ void k_rsqrt(float* __restrict__ deg) {
    int i = blockIdx.x * blockDim.x + threadIdx.x;
    if (i < NN) {
        float d = deg[i];
        deg[i] = d > 0.0f ? rsqrtf(d) : 0.0f;
    }
}

// ---------- exclusive scan of count -> rowptr (3 kernels) ----------
__global__ void k_scan1(const int* __restrict__ cnt, int* __restrict__ rowptr,
                        int* __restrict__ bsum) {
    __shared__ int s[SCAN_B];
    int i = blockIdx.x * SCAN_B + threadIdx.x;
    int v = (i < NN) ? cnt[i] : 0;
    s[threadIdx.x] = v;
    __syncthreads();
    for (int o = 1; o < SCAN_B; o <<= 1) {
        int t = (threadIdx.x >= o) ? s[threadIdx.x - o] : 0;
        __syncthreads();
        s[threadIdx.x] += t;
        __syncthreads();
    }
    if (i < NN) rowptr[i] = s[threadIdx.x] - v;  // exclusive
    if (threadIdx.x == SCAN_B - 1) bsum[blockIdx.x] = s[SCAN_B - 1];
}

__global__ void k_scan2(int* __restrict__ bsum) {   // 1 block, 128 threads
    __shared__ int s[128];
    int v = (threadIdx.x < SCAN_NB) ? bsum[threadIdx.x] : 0;
    s[threadIdx.x] = v;
    __syncthreads();
    for (int o = 1; o < 128; o <<= 1) {
        int t = (threadIdx.x >= o) ? s[threadIdx.x - o] : 0;
        __syncthreads();
        s[threadIdx.x] += t;
        __syncthreads();
    }
    if (threadIdx.x < SCAN_NB) bsum[threadIdx.x] = s[threadIdx.x] - v;  // exclusive
}

__global__ void k_scan3(int* __restrict__ rowptr, const int* __restrict__ bsum) {
    int i = blockIdx.x * blockDim.x + threadIdx.x;
    if (i < NN) rowptr[i] += bsum[i >> 10];
    if (i == 0) rowptr[NN] = NE;
}

// ---------- CSR placement: reorder (row, coeff) by destination ----------
__global__ void k_place(const int* __restrict__ row, const int* __restrict__ col,
                        const float* __restrict__ ew, const float* __restrict__ dinv,
                        const int* __restrict__ rowptr, int* __restrict__ cursor,
                        int* __restrict__ csr_src, float* __restrict__ csr_coeff) {
    int e = blockIdx.x * blockDim.x + threadIdx.x;
    if (e >= NE) return;
    int r = row[e], c = col[e];
    float cf = dinv[r] * ew[e] * dinv[c];
    int pos = rowptr[c] + atomicAdd(&cursor[c], 1);
    csr_src[pos] = r;
    csr_coeff[pos] = cf;
}

// ---------- atomic-free aggregation over F=32 features ----------
// One 64-lane wave per destination node: halves process alternating edges,
// combine via shfl_xor(32); optional fused bias+relu.
__global__ void k_agg(const int* __restrict__ rowptr, const int* __restrict__ csr_src,
                      const float* __restrict__ csr_coeff, const float* __restrict__ src,
                      const float* __restrict__ dinv, const float* __restrict__ bias,
                      float* __restrict__ out, int relu) {
    int wave = (blockIdx.x * blockDim.x + threadIdx.x) >> 6;
    if (wave >= NN) return;
    int lane = threadIdx.x & 63;
    int half = lane >> 5;
    int f = lane & 31;
    int n = wave;
    int beg = rowptr[n], end = rowptr[n + 1];
    float acc = 0.0f;
    for (int j = beg + half; j < end; j += 2) {
        int s = csr_src[j];
        float c = csr_coeff[j];
        acc = fmaf(c, src[(size_t)s * FIN + f], acc);
    }
    acc += __shfl_xor(acc, 32, 64);
    if (half == 0) {
        float di = dinv[n];
        float v = fmaf(di * di, src[(size_t)n * FIN + f], acc);
        if (bias) v += bias[f];
        if (relu) v = v > 0.0f ? v : 0.0f;
        out[(size_t)n * FIN + f] = v;
    }
}

// ---------- small dense GEMM, W staged in LDS, optional bias+relu ----------
template<int IN, int OUT, bool BR>
__global__ void k_gemm(const float* __restrict__ X, const float* __restrict__ W,
                       const float* __restrict__ b, float* __restrict__ Y) {
    __shared__ float sW[IN * OUT];
    for (int i = threadIdx.x; i < IN * OUT; i += blockDim.x) sW[i] = W[i];
    __syncthreads();
    int idx = blockIdx.x * blockDim.x + threadIdx.x;
    if (idx >= NN * OUT) return;
    int n = idx / OUT;
    int of = idx - n * OUT;
    const float* xr = X + (size_t)n * IN;
    float acc = 0.0f;
#pragma unroll
    for (int k = 0; k < IN; ++k) acc = fmaf(xr[k], sW[k * OUT + of], acc);
    if (BR) {
        acc += b[of];
        acc = acc > 0.0f ? acc : 0.0f;
    }
    Y[idx] = acc;
}

extern "C" void kernel_launch(void* const* d_in, const int* in_sizes, int n_in,
                              void* d_out, int out_size, void* d_ws, size_t ws_size,
                              hipStream_t stream) {
    const float* x  = (const float*)d_in[0];
    const int*   ei = (const int*)d_in[1];
    const float* ea = (const float*)d_in[2];
    const float* W1 = (const float*)d_in[3];
    const float* b1 = (const float*)d_in[4];
    const float* W2 = (const float*)d_in[5];
    const float* b2 = (const float*)d_in[6];
    float* out = (float*)d_out;

    const int* row = ei;        // edge_index[0]
    const int* col = ei + NE;   // edge_index[1]

    // workspace layout
    float* ws        = (float*)d_ws;
    float* deg       = ws;                         // NN (becomes dinv)
    float* agg1      = deg + NN;                   // NN*FIN
    float* h         = agg1 + (size_t)NN * FIN;    // NN*FHID
    float* hw2       = h + (size_t)NN * FHID;      // NN*FIN
    float* csr_coeff = hw2 + (size_t)NN * FIN;     // NE
    int*   csr_src   = (int*)(csr_coeff + NE);     // NE
    int*   count     = csr_src + NE;               // NN
    int*   cursor    = count + NN;                 // NN
    int*   rowptr    = cursor + NN;                // NN+1
    int*   bsum      = rowptr + NN + 1;            // 128

    const int B = 256;
    auto cdiv = [](long long a, int b) { return (int)((a + b - 1) / b); };

    hipMemsetAsync(count, 0, sizeof(int) * NN, stream);
    hipMemsetAsync(cursor, 0, sizeof(int) * NN, stream);

    // normalization + CSR build (shared by both layers)
    k_init_deg<<<cdiv(NN, B), B, 0, stream>>>(deg);
    k_hist<<<cdiv(NE, B), B, 0, stream>>>(col, ea, deg, count);
    k_rsqrt<<<cdiv(NN, B), B, 0, stream>>>(deg);
    k_scan1<<<SCAN_NB, SCAN_B, 0, stream>>>(count, rowptr, bsum);
    k_scan2<<<1, 128, 0, stream>>>(bsum);
    k_scan3<<<cdiv(NN, B), B, 0, stream>>>(rowptr, bsum);
    k_place<<<cdiv(NE, B), B, 0, stream>>>(row, col, ea, deg, rowptr, cursor,
                                           csr_src, csr_coeff);

    // layer 1: h = relu((A x) W1 + b1)   — aggregate FIRST (32 feats)
    k_agg<<<cdiv((long long)NN * 64, B), B, 0, stream>>>(
        rowptr, csr_src, csr_coeff, x, deg, nullptr, agg1, 0);
    k_gemm<FIN, FHID, true><<<cdiv((long long)NN * FHID, B), B, 0, stream>>>(
        agg1, W1, b1, h);

    // layer 2: out = relu(A (h W2) + b2) — GEMM first (64->32), then aggregate
    k_gemm<FHID, FIN, false><<<cdiv((long long)NN * FIN, B), B, 0, stream>>>(
        h, W2, nullptr, hw2);
    k_agg<<<cdiv((long long)NN * 64, B), B, 0, stream>>>(
        rowptr, csr_src, csr_coeff, hw2, deg, b2, out, 1);

    // second output: edge_attr passthrough
    hipMemcpyAsync(out + (size_t)NN * FIN, ea, sizeof(float) * (size_t)NE,
                   hipMemcpyDeviceToDevice, stream);
}

// Round 3
// 473.824 us; speedup vs baseline: 1.5309x; 1.0908x over previous
//
#include <hip/hip_runtime.h>

#define NN 100000
#define NE 1600000
#define FIN 32
#define FHID 64
#define SCAN_B 1024
#define SCAN_NB ((NN + SCAN_B - 1) / SCAN_B)   // 98
#define FIXMASK ((1ull << 40) - 1)

// ---------- fused degree+count histogram: one u64 atomic per edge ----------
// packed[c] += (1 << 40) | round(ew * 2^24)
__global__ void k_hist(const int* __restrict__ col, const float* __restrict__ ew,
                       unsigned long long* __restrict__ packed) {
    int stride = gridDim.x * blockDim.x;
    for (int e = blockIdx.x * blockDim.x + threadIdx.x; e < NE; e += stride) {
        int c = col[e];
        unsigned long long inc =
            (1ull << 40) | (unsigned long long)__float2uint_rn(ew[e] * 16777216.0f);
        atomicAdd(&packed[c], inc);
    }
}

// ---------- scan pass 1: decode packed -> (dinv, count), block-scan counts ----------
__global__ void k_scan1(const unsigned long long* __restrict__ packed,
                        float* __restrict__ dinv, int* __restrict__ rowptr,
                        int* __restrict__ bsum) {
    __shared__ int s[SCAN_B];
    int i = blockIdx.x * SCAN_B + threadIdx.x;
    unsigned long long p = (i < NN) ? packed[i] : 0ull;
    int v = (int)(p >> 40);
    if (i < NN) {
        float deg = 1.0f + (float)(p & FIXMASK) * (1.0f / 16777216.0f);
        dinv[i] = rsqrtf(deg);
    }
    s[threadIdx.x] = v;
    __syncthreads();
    for (int o = 1; o < SCAN_B; o <<= 1) {
        int t = (threadIdx.x >= o) ? s[threadIdx.x - o] : 0;
        __syncthreads();
        s[threadIdx.x] += t;
        __syncthreads();
    }
    if (i < NN) rowptr[i] = s[threadIdx.x] - v;  // exclusive
    if (threadIdx.x == SCAN_B - 1) bsum[blockIdx.x] = s[SCAN_B - 1];
}

__global__ void k_scan2(int* __restrict__ bsum) {   // 1 block, 128 threads
    __shared__ int s[128];
    int v = (threadIdx.x < SCAN_NB) ? bsum[threadIdx.x] : 0;
    s[threadIdx.x] = v;
    __syncthreads();
    for (int o = 1; o < 128; o <<= 1) {
        int t = (threadIdx.x >= o) ? s[threadIdx.x - o] : 0;
        __syncthreads();
        s[threadIdx.x] += t;
        __syncthreads();
    }
    if (threadIdx.x < SCAN_NB) bsum[threadIdx.x] = s[threadIdx.x] - v;  // exclusive
}

// finalize rowptr and seed cursor = rowptr (place then needs no rowptr read)
__global__ void k_scan3(int* __restrict__ rowptr, const int* __restrict__ bsum,
                        int* __restrict__ cursor) {
    int i = blockIdx.x * blockDim.x + threadIdx.x;
    if (i < NN) {
        int v = rowptr[i] + bsum[i >> 10];
        rowptr[i] = v;
        cursor[i] = v;
    }
    if (i == 0) rowptr[NN] = NE;
}

// ---------- CSR placement: one packed 8B record per edge ----------
// record = (src, ew * dinv[src]);  dinv[dst] factored into the agg epilogue.
__global__ void k_place(const int* __restrict__ row, const int* __restrict__ col,
                        const float* __restrict__ ew, const float* __restrict__ dinv,
                        int* __restrict__ cursor, uint2* __restrict__ csr) {
    int stride = gridDim.x * blockDim.x;
    for (int e = blockIdx.x * blockDim.x + threadIdx.x; e < NE; e += stride) {
        int r = row[e], c = col[e];
        float cf = ew[e] * dinv[r];
        int pos = atomicAdd(&cursor[c], 1);
        csr[pos] = make_uint2((unsigned)r, __float_as_uint(cf));
    }
}

// ---------- atomic-free aggregation over F=32 features ----------
// One 64-lane wave per destination node; halves process alternating edges,
// combine via shfl_xor(32).  out[n] = dinv[n]*(acc + dinv[n]*x[n]) (+b, relu)
__global__ void k_agg(const int* __restrict__ rowptr, const uint2* __restrict__ csr,
                      const float* __restrict__ src, const float* __restrict__ dinv,
                      const float* __restrict__ bias, float* __restrict__ out, int relu) {
    int wave = (blockIdx.x * blockDim.x + threadIdx.x) >> 6;
    if (wave >= NN) return;
    int lane = threadIdx.x & 63;
    int half = lane >> 5;
    int f = lane & 31;
    int n = wave;
    int beg = rowptr[n], end = rowptr[n + 1];
    float acc = 0.0f;
    for (int j = beg + half; j < end; j += 2) {
        uint2 p = csr[j];
        acc = fmaf(__uint_as_float(p.y), src[(size_t)p.x * FIN + f], acc);
    }
    acc += __shfl_xor(acc, 32, 64);
    if (half == 0) {
        float di = dinv[n];
        float v = di * fmaf(di, src[(size_t)n * FIN + f], acc);
        if (bias) v += bias[f];
        if (relu) v = v > 0.0f ? v : 0.0f;
        out[(size_t)n * FIN + f] = v;
    }
}

// ---------- small dense GEMM, W staged in LDS, optional bias+relu ----------
template<int IN, int OUT, bool BR>
__global__ void k_gemm(const float* __restrict__ X, const float* __restrict__ W,
                       const float* __restrict__ b, float* __restrict__ Y) {
    __shared__ float sW[IN * OUT];
    for (int i = threadIdx.x; i < IN * OUT; i += blockDim.x) sW[i] = W[i];
    __syncthreads();
    int idx = blockIdx.x * blockDim.x + threadIdx.x;
    if (idx >= NN * OUT) return;
    int n = idx / OUT;
    int of = idx - n * OUT;
    const float* xr = X + (size_t)n * IN;
    float acc = 0.0f;
#pragma unroll
    for (int k = 0; k < IN; ++k) acc = fmaf(xr[k], sW[k * OUT + of], acc);
    if (BR) {
        acc += b[of];
        acc = acc > 0.0f ? acc : 0.0f;
    }
    Y[idx] = acc;
}

extern "C" void kernel_launch(void* const* d_in, const int* in_sizes, int n_in,
                              void* d_out, int out_size, void* d_ws, size_t ws_size,
                              hipStream_t stream) {
    const float* x  = (const float*)d_in[0];
    const int*   ei = (const int*)d_in[1];
    const float* ea = (const float*)d_in[2];
    const float* W1 = (const float*)d_in[3];
    const float* b1 = (const float*)d_in[4];
    const float* W2 = (const float*)d_in[5];
    const float* b2 = (const float*)d_in[6];
    float* out = (float*)d_out;

    const int* row = ei;        // edge_index[0]
    const int* col = ei + NE;   // edge_index[1]

    // workspace layout (8B-aligned items first)
    char* w = (char*)d_ws;
    unsigned long long* packed = (unsigned long long*)w;        // NN * 8B
    uint2* csr   = (uint2*)(w + (size_t)NN * 8);                // NE * 8B
    float* dinv  = (float*)(w + (size_t)NN * 8 + (size_t)NE * 8);  // NN
    int*   rowptr = (int*)(dinv + NN);                          // NN + 1
    int*   cursor = rowptr + NN + 1;                            // NN
    int*   bsum   = cursor + NN;                                // 128
    float* agg1   = (float*)(bsum + 128);                       // NN*FIN
    float* h      = agg1 + (size_t)NN * FIN;                    // NN*FHID
    float* hw2    = h + (size_t)NN * FHID;                      // NN*FIN

    const int B = 256;
    auto cdiv = [](long long a, int b) { return (int)((a + b - 1) / b); };

    // edge_attr passthrough first (independent)
    hipMemcpyAsync(out + (size_t)NN * FIN, ea, sizeof(float) * (size_t)NE,
                   hipMemcpyDeviceToDevice, stream);

    hipMemsetAsync(packed, 0, sizeof(unsigned long long) * NN, stream);

    // normalization + CSR build (shared by both layers)
    k_hist<<<2048, B, 0, stream>>>(col, ea, packed);
    k_scan1<<<SCAN_NB, SCAN_B, 0, stream>>>(packed, dinv, rowptr, bsum);
    k_scan2<<<1, 128, 0, stream>>>(bsum);
    k_scan3<<<cdiv(NN, B), B, 0, stream>>>(rowptr, bsum, cursor);
    k_place<<<2048, B, 0, stream>>>(row, col, ea, dinv, cursor, csr);

    // layer 1: h = relu((A x) W1 + b1)   — aggregate FIRST (32 feats)
    k_agg<<<cdiv((long long)NN * 64, B), B, 0, stream>>>(
        rowptr, csr, x, dinv, nullptr, agg1, 0);
    k_gemm<FIN, FHID, true><<<cdiv((long long)NN * FHID, B), B, 0, stream>>>(
        agg1, W1, b1, h);

    // layer 2: out = relu(A (h W2) + b2) — GEMM first (64->32), then aggregate
    k_gemm<FHID, FIN, false><<<cdiv((long long)NN * FIN, B), B, 0, stream>>>(
        h, W2, nullptr, hw2);
    k_agg<<<cdiv((long long)NN * 64, B), B, 0, stream>>>(
        rowptr, csr, hw2, dinv, b2, out, 1);
}